// Round 5
// baseline (203.529 us; speedup 1.0000x reference)
//
#include <hip/hip_runtime.h>
#include <hip/hip_bf16.h>

typedef __bf16 bf16_t;
typedef __bf16 bf16x8 __attribute__((ext_vector_type(8)));
typedef float  floatx4 __attribute__((ext_vector_type(4)));

#define BQ 16
#define NTOK 2048
#define DIM 256
#define HD 64

// ---------------- Kernel 0: W -> W^T bf16, + zero out-accumulator & rowsums ----------------
__global__ __launch_bounds__(256) void k_prep(const float* __restrict__ Wq,
                                              const float* __restrict__ Wk,
                                              const float* __restrict__ Wv,
                                              bf16_t* __restrict__ wt,
                                              float* __restrict__ outz,
                                              float* __restrict__ rsz) {
    int o = blockIdx.x * 256 + threadIdx.x;   // grid 1024 -> o < 262144
    if (o < 49152) {
        int w = o >> 14;
        int r = o & 16383;
        int h = r >> 8;
        int d = r & 255;
        const float* W = (w == 0) ? Wq : ((w == 1) ? Wk : Wv);
        wt[o] = (bf16_t)W[d * 64 + h];
    }
    // zero out (524288 float4) + rs (8192 float4)
    float4 z = make_float4(0.f, 0.f, 0.f, 0.f);
    for (int u = o; u < 532480; u += 262144) {
        if (u < 524288) ((float4*)outz)[u] = z;
        else            ((float4*)rsz)[u - 524288] = z;
    }
}

// ---------------- Kernel 1: QKV projection (64 tokens/block, 512 blocks) ----------------
#define XS 264
__global__ __launch_bounds__(256) void k_qkv(const float* __restrict__ x,
                                             const bf16_t* __restrict__ wt,
                                             const float* __restrict__ bq,
                                             const float* __restrict__ bk,
                                             const float* __restrict__ bv,
                                             bf16_t* __restrict__ qb,
                                             bf16_t* __restrict__ kb,
                                             bf16_t* __restrict__ vt) {
    __shared__ bf16_t x_ls[64 * XS];
    __shared__ bf16_t vt_ls[64 * 72];

    int b  = blockIdx.x >> 5;
    int t0 = (blockIdx.x & 31) << 6;
    int t  = threadIdx.x;
    int lane = t & 63;
    int w    = t >> 6;
    int m_   = lane & 15;
    int q4   = lane >> 4;

    for (int tau = t; tau < 4096; tau += 256) {
        int row = tau >> 6, ch = tau & 63;
        float4 v = ((const float4*)x)[(size_t)(b * NTOK + t0 + row) * 64 + ch];
        bf16_t tmp[4] = {(bf16_t)v.x, (bf16_t)v.y, (bf16_t)v.z, (bf16_t)v.w};
        *(uint2*)(&x_ls[row * XS + ch * 4]) = *(uint2*)tmp;
    }
    __syncthreads();

    for (int wi = 0; wi < 3; ++wi) {
        const bf16_t* wtw = wt + wi * 16384;
        floatx4 acc[4];
        #pragma unroll
        for (int mt = 0; mt < 4; ++mt) acc[mt] = floatx4{0.f, 0.f, 0.f, 0.f};

        #pragma unroll
        for (int ks = 0; ks < 8; ++ks) {
            bf16x8 bfrag = *(const bf16x8*)(wtw + (16 * w + m_) * 256 + ks * 32 + q4 * 8);
            #pragma unroll
            for (int mt = 0; mt < 4; ++mt) {
                bf16x8 afrag = *(const bf16x8*)(&x_ls[(16 * mt + m_) * XS + ks * 32 + q4 * 8]);
                acc[mt] = __builtin_amdgcn_mfma_f32_16x16x32_bf16(afrag, bfrag, acc[mt], 0, 0, 0);
            }
        }
        const float* bias_p = (wi == 0) ? bq : ((wi == 1) ? bk : bv);
        float bias = bias_p[16 * w + m_];
        float scale = (wi == 0) ? 0.125f : 1.0f;   // fold H^-0.5 into q (exact pow2)

        if (wi < 2) {
            bf16_t* dst = (wi == 0) ? qb : kb;
            #pragma unroll
            for (int mt = 0; mt < 4; ++mt)
                #pragma unroll
                for (int r = 0; r < 4; ++r) {
                    int tok = t0 + 16 * mt + 4 * q4 + r;
                    dst[(size_t)(b * NTOK + tok) * 64 + 16 * w + m_] = (bf16_t)((acc[mt][r] + bias) * scale);
                }
        } else {
            #pragma unroll
            for (int mt = 0; mt < 4; ++mt)
                #pragma unroll
                for (int r = 0; r < 4; ++r)
                    vt_ls[(16 * w + m_) * 72 + 16 * mt + 4 * q4 + r] = (bf16_t)(acc[mt][r] + bias);
            __syncthreads();
            for (int tau = t; tau < 512; tau += 256) {
                int h = tau >> 3, ch = tau & 7;
                uint4 val = *(const uint4*)(&vt_ls[h * 72 + ch * 8]);
                *(uint4*)(vt + (size_t)(b * 64 + h) * NTOK + t0 + ch * 8) = val;
            }
        }
    }
}

// ---------------- Kernel 2: fused attention, 64x64 frame, conv on MFMA pipe ----------------
// Round-5: rounds 2/3/4 proved VALU-issue-bound (VALU-busy time pinned at 63-66 us
// across barrier/LDS/occupancy changes). The 9-FMA/element 3x3 conv was ~half the
// VALU stream while MfmaUtil sat at 7%. Conv is now Sum_di Shift(A,di) @ B_di with
// banded constant B-fragments (3 MFMA per output tile), A stored bf16 in LDS.
#define SP 72
#define RINT 62
#define L2E 1.44269504f

static __device__ __forceinline__ bf16x8 as_bf16x8(uint4 u) {
    union { uint4 a; bf16x8 b; } c; c.a = u; return c.b;
}

// (512,3): pin VGPR budget to ~85 (6 waves/SIMD = 3 blocks/CU). Round-1 calibration:
// hipcc treats the 2nd arg as blocks/CU here ((512,6) -> 40 VGPR = 12 waves/SIMD).
__global__ __launch_bounds__(512, 3) void k_attn(const bf16_t* __restrict__ qb,
                                                 const bf16_t* __restrict__ kb,
                                                 const bf16_t* __restrict__ vt,
                                                 const float* __restrict__ conv_w,
                                                 const float* __restrict__ conv_b,
                                                 float* __restrict__ outp,
                                                 float* __restrict__ rsg) {
    __shared__ bf16_t k_ls[64 * SP];       // 9216 B  K [frame col j][ch]  (single buffer: writes post-B1, reads post-B2)
    __shared__ bf16_t v_ls[64 * SP];       // 9216 B  V [h][k]
    __shared__ bf16_t a_bf[64 * SP];       // 9216 B  QK^T tile, bf16 (conv MFMA operand)
    __shared__ bf16_t p_raw[64 * SP + 8];  // 9232 B  P; +8 guard pad for col -1 stores
    bf16_t* pv_ls = p_raw + 8;             // total LDS 36880 B

    int b  = blockIdx.z;
    int r0 = blockIdx.x * RINT;
    int cy = blockIdx.y;
    int it_beg = (cy * 34) / 3;            // chunks {11,11,12}
    int it_end = ((cy + 1) * 34) / 3;

    int t = threadIdx.x, lane = t & 63, w = t >> 6;
    int m_ = lane & 15, q4 = lane >> 4;
    int wtj = w & 3;             // col tile 0..3
    int wti = (w >> 2) << 1;     // row tile base {0,2}

    const uint* vt32 = (const uint*)vt + (size_t)b * 64 * 1024;
    const bf16_t* kb_b = kb + (size_t)b * NTOK * 64;

    int krow = t >> 3, kch = t & 7;

    uint4 kreg;
    uint  vreg[4];
    auto load_k = [&](int c0) {
        int g = c0 - 1 + krow;
        uint4 val = make_uint4(0u, 0u, 0u, 0u);
        if (g >= 0 && g < NTOK)
            val = *(const uint4*)(kb_b + (size_t)g * 64 + kch * 8);
        kreg = val;
    };
    auto load_v = [&](int c0) {
        int cb2 = (c0 >> 1) + 4 * kch;     // c0 always even
        #pragma unroll
        for (int j = 0; j < 4; ++j) {
            uint val = 0u;
            if (cb2 + j < 1024) val = vt32[krow * 1024 + cb2 + j];
            vreg[j] = val;
        }
    };

    load_k(it_beg * RINT);
    load_v(it_beg * RINT);

    // ---- banded conv B-fragments (built once; weights * L2E, bf16) ----
    // B_di(k,n) = w[di][k-n+1] for |k-n|<=1. Lane supplies B[k=koff+q4*8+jj][n=16*wtj+m_].
    // K=32 window start per col-tile: koff = {0,8,24,32}.
    float cw9[9];
    #pragma unroll
    for (int i = 0; i < 9; ++i) cw9[i] = conv_w[i] * L2E;
    float cbv2 = conv_b[0] * L2E;
    int koff = ((wtj & 1) << 3) + ((wtj & 2) * 12);
    bf16x8 bK[3];
    #pragma unroll
    for (int di = 0; di < 3; ++di) {
        bf16_t tmp[8];
        #pragma unroll
        for (int jj = 0; jj < 8; ++jj) {
            int d = koff + q4 * 8 + jj - (16 * wtj + m_) + 1;
            tmp[jj] = (bf16_t)((d >= 0 && d < 3) ? cw9[3 * di + d] : 0.f);
        }
        bK[di] = *(bf16x8*)tmp;
    }

    // Q fragments -> registers (loaded once)
    bf16x8 qreg[2][2];
    #pragma unroll
    for (int p = 0; p < 2; ++p) {
        int g = r0 - 1 + 16 * (wti + p) + m_;
        #pragma unroll
        for (int ks = 0; ks < 2; ++ks) {
            uint4 val = make_uint4(0u, 0u, 0u, 0u);
            if (g >= 0 && g < NTOK)
                val = *(const uint4*)(qb + (size_t)(b * NTOK + g) * 64 + ks * 32 + q4 * 8);
            qreg[p][ks] = as_bf16x8(val);
        }
    }

    // one-time zero init of P (col 63 relies on this; cols 0..62 rewritten every iter)
    for (int u = t; u < 2308; u += 512) ((uint*)p_raw)[u] = 0u;

    // prologue: K[it_beg] -> k_ls; start K[it_beg+1]
    *(uint4*)(&k_ls[krow * SP + kch * 8]) = kreg;
    load_k((it_beg + 1) * RINT);

    floatx4 accO[2], rsacc[2];
    accO[0] = floatx4{0.f, 0.f, 0.f, 0.f};
    accO[1] = floatx4{0.f, 0.f, 0.f, 0.f};
    rsacc[0] = floatx4{0.f, 0.f, 0.f, 0.f};
    rsacc[1] = floatx4{0.f, 0.f, 0.f, 0.f};

    // col mask: frame col j=0 (prev chunk's) and j=63 (rim) contribute nothing
    float mj = ((wtj == 0 && m_ == 0) || (wtj == 3 && m_ == 15)) ? 0.f : 1.f;
    int jm1 = 16 * wtj + m_ - 1;           // P column (store target); -1 lands in guard pad

    __syncthreads();

    for (int itg = it_beg; itg < it_end; ++itg) {
        // ---- QK^T: 2 tiles/wave, K=64; D kept fp32 in regs, stored bf16 to a_bf ----
        floatx4 areg[2];
        {
            bf16x8 bfr0 = *(const bf16x8*)(&k_ls[(16 * wtj + m_) * SP + q4 * 8]);
            bf16x8 bfr1 = *(const bf16x8*)(&k_ls[(16 * wtj + m_) * SP + 32 + q4 * 8]);
            #pragma unroll
            for (int p = 0; p < 2; ++p) {
                floatx4 a = floatx4{0.f, 0.f, 0.f, 0.f};
                a = __builtin_amdgcn_mfma_f32_16x16x32_bf16(qreg[p][0], bfr0, a, 0, 0, 0);
                a = __builtin_amdgcn_mfma_f32_16x16x32_bf16(qreg[p][1], bfr1, a, 0, 0, 0);
                areg[p] = a;
                int rbase = 16 * (wti + p) + 4 * q4;
                #pragma unroll
                for (int r = 0; r < 4; ++r)
                    a_bf[(rbase + r) * SP + 16 * wtj + m_] = (bf16_t)a[r];
            }
        }
        __syncthreads();   // B1

        // ---- stage K[itg+1] -> k_ls (QK^T reads done), V[itg] -> v_ls; issue next loads ----
        *(uint4*)(&k_ls[krow * SP + kch * 8]) = kreg;
        *(uint4*)(&v_ls[krow * SP + 8 * kch]) = make_uint4(vreg[0], vreg[1], vreg[2], vreg[3]);
        load_k((itg + 2) * RINT);
        load_v((itg + 1) * RINT);

        // ---- conv via 3 chained MFMA per tile + element ops (sig/relu/expm1) ----
        #pragma unroll
        for (int p = 0; p < 2; ++p) {
            int arow = 16 * (wti + p) + m_ - 1;
            floatx4 c = floatx4{cbv2, cbv2, cbv2, cbv2};
            #pragma unroll
            for (int di = 0; di < 3; ++di) {
                bf16x8 af = *(const bf16x8*)(&a_bf[((arow + di) & 63) * SP + koff + q4 * 8]);
                c = __builtin_amdgcn_mfma_f32_16x16x32_bf16(af, bK[di], c, 0, 0, 0);
            }
            int rbase = 16 * (wti + p) + 4 * q4;
            #pragma unroll
            for (int r = 0; r < 4; ++r) {
                float sig = __builtin_amdgcn_rcpf(1.f + __builtin_amdgcn_exp2f(-c[r]));
                float s = fmaxf(areg[p][r] - sig, 0.f);
                float ev = (__builtin_amdgcn_exp2f(s * L2E) - 1.f) * mj;
                if (p == 0 && r == 0) { if (wti == 0) ev = (q4 == 0) ? 0.f : ev; }  // frame row 0
                if (p == 1 && r == 3) { if (wti == 2) ev = (q4 == 3) ? 0.f : ev; }  // frame row 63
                rsacc[p][r] += ev;
                pv_ls[(rbase + r) * SP + jm1] = (bf16_t)ev;
            }
        }
        __syncthreads();   // B2

        // ---- PV: O[64x64] += P @ V, 2 tiles/wave (no barrier after: all next-iter
        //      LDS writes are post-B1[it+1], reached only after every wave's PV here) ----
        #pragma unroll
        for (int ks = 0; ks < 2; ++ks) {
            bf16x8 bfr = *(const bf16x8*)(&v_ls[(16 * wtj + m_) * SP + ks * 32 + q4 * 8]);
            #pragma unroll
            for (int p = 0; p < 2; ++p) {
                bf16x8 af = *(const bf16x8*)(&pv_ls[(16 * (wti + p) + m_) * SP + ks * 32 + q4 * 8]);
                accO[p] = __builtin_amdgcn_mfma_f32_16x16x32_bf16(af, bfr, accO[p], 0, 0, 0);
            }
        }
    }

    // ---- epilogue: rowsum (reduce over 16 m_ lanes; 4 col-waves add atomically) ----
    #pragma unroll
    for (int p = 0; p < 2; ++p)
        #pragma unroll
        for (int r = 0; r < 4; ++r) {
            float s = rsacc[p][r];
            s += __shfl_xor(s, 1);
            s += __shfl_xor(s, 2);
            s += __shfl_xor(s, 4);
            s += __shfl_xor(s, 8);
            if (m_ == 0) {
                int grow = r0 + 16 * (wti + p) + 4 * q4 + r - 1;
                if ((unsigned)grow < NTOK) atomicAdd(&rsg[b * NTOK + grow], s);
            }
        }

    // ---- epilogue: partial O -> atomic ----
    #pragma unroll
    for (int p = 0; p < 2; ++p) {
        int rbase = 16 * (wti + p) + 4 * q4;
        #pragma unroll
        for (int r = 0; r < 4; ++r) {
            int i = rbase + r;
            int grow = r0 + i - 1;
            if (i >= 1 && i < 63 && grow < NTOK)
                atomicAdd(&outp[((size_t)(b * NTOK + grow) << 6) + 16 * wtj + m_], accO[p][r]);
        }
    }
}

// ---------------- Kernel 3: normalize out /= (rowsum + eps), in place ----------------
__global__ __launch_bounds__(256) void k_norm(float* __restrict__ out,
                                              const float* __restrict__ rsg) {
    int gid = blockIdx.x * 256 + threadIdx.x;   // 524288 float4s
    float4 o = ((float4*)out)[gid];
    float d = rsg[gid >> 4] + 1e-5f;
    float inv = 1.f / d;
    o.x *= inv; o.y *= inv; o.z *= inv; o.w *= inv;
    ((float4*)out)[gid] = o;
}

extern "C" void kernel_launch(void* const* d_in, const int* in_sizes, int n_in,
                              void* d_out, int out_size, void* d_ws, size_t ws_size,
                              hipStream_t stream) {
    const float* x  = (const float*)d_in[0];
    const float* Wq = (const float*)d_in[1];
    const float* bq = (const float*)d_in[2];
    const float* Wk = (const float*)d_in[3];
    const float* bk = (const float*)d_in[4];
    const float* Wv = (const float*)d_in[5];
    const float* bv = (const float*)d_in[6];
    const float* cw = (const float*)d_in[7];
    const float* cb = (const float*)d_in[8];
    float* out = (float*)d_out;

    char* ws = (char*)d_ws;
    bf16_t* wt = (bf16_t*)ws;                               // 98304 B
    bf16_t* qb = (bf16_t*)(ws + 98304);                     // 4 MB
    bf16_t* kb = (bf16_t*)(ws + 98304 + 4194304);           // 4 MB
    bf16_t* vt = (bf16_t*)(ws + 98304 + 8388608);           // 4 MB
    float*  rsg = (float*)(ws + 98304 + 12582912);          // 128 KB

    k_prep<<<dim3(1024), dim3(256), 0, stream>>>(Wq, Wk, Wv, wt, out, rsg);
    k_qkv<<<dim3(512), dim3(256), 0, stream>>>(x, wt, bq, bk, bv, qb, kb, vt);
    k_attn<<<dim3(34, 3, BQ), dim3(512), 0, stream>>>(qb, kb, vt, cw, cb, out, rsg);
    k_norm<<<dim3(2048), dim3(256), 0, stream>>>(out, rsg);
}